// Round 7
// baseline (131.655 us; speedup 1.0000x reference)
//
#include <hip/hip_runtime.h>

typedef __attribute__((ext_vector_type(8))) short short8;
typedef __attribute__((ext_vector_type(4))) float f32x4;

__device__ __forceinline__ unsigned short f2bf(float f) {
    unsigned int u = __float_as_uint(f);
    unsigned int r = u + 0x7fffu + ((u >> 16) & 1u);  // RNE
    return (unsigned short)(r >> 16);
}

__device__ __forceinline__ float bf2f(short s) {
    return __uint_as_float(((unsigned int)(unsigned short)s) << 16);
}

// tanh-form gelu: x * sigmoid(2*sqrt(2/pi)*(x + 0.044715 x^3))
__device__ __forceinline__ float gelu_fast(float v) {
    float x2 = v * v;
    float s  = v * fmaf(-0.102943195f, x2, -2.3022077f);   // -2z*log2(e)
    float e  = __builtin_amdgcn_exp2f(s);
    return v * __builtin_amdgcn_rcpf(1.0f + e);
}

__device__ __forceinline__ unsigned int d2key(float d2) {
    unsigned int u = __float_as_uint(d2);
    return u ^ (((unsigned int)(((int)u) >> 31)) | 0x80000000u);
}

#define U64MAX 0xFFFFFFFFFFFFFFFFull

// FROZEN (R5/R7/R9-passing byte-form), parameterized operand names only —
// the op sequence (__fmul_rn/__fadd_rn/fmaf) is byte-identical. Do not touch.
// Evaluated ONLY for candidates (~20-30/query); hot scans use the provably
// superset approximate prefilter (KNN_SLACK below).
#define D2_FROM_Q(px, py, XI, YI, SQI)                                           \
    ({ const float sqj_ = __fadd_rn(__fmul_rn((px), (px)), __fmul_rn((py), (py))); \
       const float t_   = fmaf((YI), (py), __fmul_rn((XI), (px)));                 \
       const float s_   = __fadd_rn((SQI), sqj_);                                  \
       fmaf(-2.0f, t_, s_); })

__device__ __forceinline__ unsigned long long bitonic64(unsigned long long v, int lane) {
#pragma unroll
    for (int k = 2; k <= 64; k <<= 1) {
#pragma unroll
        for (int j = k >> 1; j > 0; j >>= 1) {
            unsigned long long pv = __shfl_xor(v, j, 64);
            const bool up  = ((lane & k) == 0);
            const bool low = ((lane & j) == 0);
            const unsigned long long mn = (v < pv) ? v : pv;
            const unsigned long long mx = (v < pv) ? pv : v;
            v = (up == low) ? mn : mx;
        }
    }
    return v;
}

// float version for the threshold phase only.
__device__ __forceinline__ float bitonic64f(float v, int lane) {
#pragma unroll
    for (int k = 2; k <= 64; k <<= 1) {
#pragma unroll
        for (int j = k >> 1; j > 0; j >>= 1) {
            float pv = __shfl_xor(v, j, 64);
            const bool up  = ((lane & k) == 0);
            const bool low = ((lane & j) == 0);
            const float mn = fminf(v, pv);
            const float mx = fmaxf(v, pv);
            v = (up == low) ? mn : mx;
        }
    }
    return v;
}

// Exact-path candidate insertion: recompute FROZEN d2 + key, push to LDS.
__device__ __forceinline__ void insert_cand(
        unsigned long long* crow, int* cnt,
        float px, float py, float XI, float YI, float SQI, int i) {
    const float d2 = D2_FROM_Q(px, py, XI, YI, SQI);
    const unsigned int key = d2key(d2);
    int pos = atomicAdd(cnt, 1);
    if (pos < 128)
        crow[pos] = ((unsigned long long)key << 32) | (unsigned int)i;
}

// Superset-prefilter slack (see R1 derivation: approx-metric deviation from
// (exact d2 - sqi) is ~2e-5; 100x margin -> provable superset incl. ties).
#define KNN_SLACK 2.0e-3f

// ---------------- K1: wconv (blocks 0..383) + knn (blocks 384..2431) ----------
// R6-verbatim (measured 131.28 us config). knn: 4 waves x 4 queries, wave wv
// scans float4s [wv*1024, +1024); scan-2 branch-fold (neutral, kept).
__global__ __launch_bounds__(256) void knn_kernel(
        const float* __restrict__ points,
        const float* __restrict__ W1, const float* __restrict__ W2,
        unsigned short* __restrict__ W1t, unsigned short* __restrict__ W2t,
        int* __restrict__ idx_out) {
    __shared__ float pmin[4][4][64];          // [query][wave][lane]
    __shared__ float tshr[4];
    __shared__ unsigned long long cand[4][128];
    __shared__ int ccnt[4];

    const int bid = blockIdx.x;
    const int tid = threadIdx.x;

    if (bid < 384) {                       // ---- wconv ----
        int g = bid * 256 + tid;
        if (g < 65536) {                   // W1: (256,256) -> W1t[c][d]
            int d = g >> 8, c = g & 255;
            W1t[c * 256 + d] = f2bf(W1[g]);
        } else if (g < 98304) {            // W2: (256,128) -> W2t[c][d]
            int g2 = g - 65536;
            int d = g2 >> 7, c = g2 & 127;
            W2t[c * 256 + d] = f2bf(W2[g2]);
        }
        return;
    }

    // ---- knn: 4 waves, 4 queries, each wave scans points [wv*2048,(wv+1)*2048)
    const int wv    = tid >> 6;
    const int lane  = tid & 63;
    const int qbase = (bid - 384) << 2;

    float xi[4], yi[4], sqi_[4], n2x[4], n2y[4];
#pragma unroll
    for (int t = 0; t < 4; ++t) {
        xi[t] = points[(qbase + t) * 2 + 0];
        yi[t] = points[(qbase + t) * 2 + 1];
        sqi_[t] = __fadd_rn(__fmul_rn(xi[t], xi[t]), __fmul_rn(yi[t], yi[t]));
        n2x[t] = -2.0f * xi[t];
        n2y[t] = -2.0f * yi[t];
    }

    const float4* p4 = (const float4*)points;     // 2 points per float4
    const float4* pw = p4 + wv * 1024 + lane;     // this wave's slice

    if (tid < 4) ccnt[tid] = 0;

    // ---- scan 1: per-lane minimum of approx metric, per query ----
    float vmn[4] = {1e30f, 1e30f, 1e30f, 1e30f};
#pragma unroll 4
    for (int j = 0; j < 16; ++j) {
        const float4 pp = pw[j * 64];
        const float sqa = fmaf(pp.x, pp.x, pp.y * pp.y);
        const float sqb = fmaf(pp.z, pp.z, pp.w * pp.w);
#pragma unroll
        for (int t = 0; t < 4; ++t) {
            const float da = fmaf(n2x[t], pp.x, fmaf(n2y[t], pp.y, sqa));
            const float db = fmaf(n2x[t], pp.z, fmaf(n2y[t], pp.w, sqb));
            vmn[t] = fminf(fminf(da, db), vmn[t]);   // v_min3 candidate
        }
    }
#pragma unroll
    for (int t = 0; t < 4; ++t) pmin[t][wv][lane] = vmn[t];
    __syncthreads();

    // ---- 17th-smallest combined lane-min + slack = safe superset threshold --
    {
        const int q = wv;                      // one query per wave
        const float m = fminf(fminf(pmin[q][0][lane], pmin[q][1][lane]),
                              fminf(pmin[q][2][lane], pmin[q][3][lane]));
        const float s = bitonic64f(m, lane);
        if (lane == 16) tshr[q] = s + KNN_SLACK;
    }
    __syncthreads();
    float Ta[4];
#pragma unroll
    for (int t = 0; t < 4; ++t) Ta[t] = tshr[t];

    // ---- scan 2: approx prefilter, exact FROZEN recompute on hit ----
#pragma unroll 4
    for (int j = 0; j < 16; ++j) {
        const float4 pp = pw[j * 64];
        const int i0 = (wv * 1024 + j * 64 + lane) * 2;
        const float sqa = fmaf(pp.x, pp.x, pp.y * pp.y);
        const float sqb = fmaf(pp.z, pp.z, pp.w * pp.w);
#pragma unroll
        for (int t = 0; t < 4; ++t) {
            const float da = fmaf(n2x[t], pp.x, fmaf(n2y[t], pp.y, sqa));
            const float db = fmaf(n2x[t], pp.z, fmaf(n2y[t], pp.w, sqb));
            if (fminf(da, db) <= Ta[t]) {
                if (da <= Ta[t])
                    insert_cand(cand[t], &ccnt[t],
                                pp.x, pp.y, xi[t], yi[t], sqi_[t], i0);
                if (db <= Ta[t])
                    insert_cand(cand[t], &ccnt[t],
                                pp.z, pp.w, xi[t], yi[t], sqi_[t], i0 + 1);
            }
        }
    }
    __syncthreads();

    // ---- extraction (R9-verbatim, one query per wave) ----
    {
        const int q = qbase + wv;
        unsigned long long* candw = cand[wv];
        const int cc = ccnt[wv];
        const int n = cc < 128 ? cc : 128;
        if (n <= 64) {
            // fast path: full sort of candidates; lane k holds k-th smallest
            unsigned long long v0 = (lane < n) ? candw[lane] : U64MAX;
            v0 = bitonic64(v0, lane);
            if (lane >= 1 && lane <= 16)
                idx_out[q * 16 + lane - 1] = (int)(unsigned int)(v0 & 0xFFFFFFFFull);
        } else {
            // slow path: 17 iterated wave-min extractions
            unsigned long long v0 = (lane < n)      ? candw[lane]      : U64MAX;
            unsigned long long v1 = (lane + 64 < n) ? candw[lane + 64] : U64MAX;
#pragma unroll 1
            for (int pick = 0; pick < 17; ++pick) {
                unsigned long long m = (v0 < v1) ? v0 : v1;
#pragma unroll
                for (int d = 1; d < 64; d <<= 1) {
                    unsigned long long pm = __shfl_xor(m, d, 64);
                    m = (pm < m) ? pm : m;
                }
                if (pick > 0 && lane == 0)
                    idx_out[q * 16 + pick - 1] = (int)(unsigned int)(m & 0xFFFFFFFFull);
                if (v0 == m) v0 = U64MAX;
                else if (v1 == m) v1 = U64MAX;
            }
        }
    }
}

// ---------------- K2: A = x@W1[:128], D = x@W1[128:] - A + b1 (bf16) ----------
// R7 single-variable experiment: R4's K2 rework, isolated this time.
// (a) 512 blocks, 64x64 tiles -> 2 waves/SIMD (R9 form was 256 blocks = 1
// wave/SIMD, zero TLP); (b) epilogue staged through LDS -> 4 coalesced short8
// stores/thread (R9 form: 128 scalar 2-byte column-scatter stores/thread).
// Per-output MFMA sequence (ks order, fragments, f2bf) IDENTICAL to R9 ->
// bit-same outputs (HW-validated in the R4 bundle).
__global__ __launch_bounds__(256) void gemmAD_kernel(
        const float* __restrict__ x, const unsigned short* __restrict__ W1t,
        const float* __restrict__ b1,
        unsigned short* __restrict__ Abf, unsigned short* __restrict__ Dbf) {
    __shared__ unsigned short sx[64 * 136];    // 64 rows x 128 bf16, stride 136
    __shared__ unsigned short tA[64 * 68];     // 64 x 64 out tile, stride 68
    __shared__ unsigned short tD[64 * 68];
    const int tid = threadIdx.x;
    const int rb  = (blockIdx.x >> 2) * 64;    // 128 row-tiles
    const int cb  = (blockIdx.x & 3) * 64;     // 4 col-tiles

    {   // stage x rows -> bf16 LDS (unchanged)
        const int r   = ((tid >> 6) << 4) | (tid & 15);   // row 0..63
        const int seg = (tid >> 4) & 3;                   // 32-float segment
        const float* xr = x + (rb + r) * 128 + seg * 32;
        unsigned short* dst = sx + r * 136 + seg * 32;
#pragma unroll
        for (int u = 0; u < 8; ++u) {
            float4 a = ((const float4*)xr)[u];
            uint2 w;
            w.x = (unsigned)f2bf(a.x) | ((unsigned)f2bf(a.y) << 16);
            w.y = (unsigned)f2bf(a.z) | ((unsigned)f2bf(a.w) << 16);
            *(uint2*)(dst + u * 4) = w;
        }
    }
    __syncthreads();

    const int lane = tid & 63, wv = tid >> 6;
    const int m = lane & 15, quad = lane >> 4;
    const int ko0 = quad * 8;

    f32x4 accA[4], accC[4];
#pragma unroll
    for (int i = 0; i < 4; ++i) { accA[i] = (f32x4){0,0,0,0}; accC[i] = (f32x4){0,0,0,0}; }

    const int colL = wv * 16 + m;              // local col 0..63

#pragma unroll
    for (int ks = 0; ks < 4; ++ks) {
        const int ko = ks * 32 + ko0;
        short8 af[4];
#pragma unroll
        for (int rt = 0; rt < 4; ++rt)
            af[rt] = *(const short8*)(sx + (rt * 16 + m) * 136 + ko);
        const unsigned short* wp = W1t + (cb + colL) * 256 + ko;
        const short8 bA = *(const short8*)(wp);         // d in [0,128)  -> A
        const short8 bC = *(const short8*)(wp + 128);   // d in [128,256)-> C
#pragma unroll
        for (int rt = 0; rt < 4; ++rt) {
            accA[rt] = __builtin_amdgcn_mfma_f32_16x16x32_bf16(af[rt], bA, accA[rt], 0, 0, 0);
            accC[rt] = __builtin_amdgcn_mfma_f32_16x16x32_bf16(af[rt], bC, accC[rt], 0, 0, 0);
        }
    }

    // epilogue: acc -> LDS tiles (bit-same values as R9 path)
    {
        const float bias = b1[cb + colL];
#pragma unroll
        for (int rt = 0; rt < 4; ++rt)
#pragma unroll
            for (int j = 0; j < 4; ++j) {
                const int rowL = rt * 16 + quad * 4 + j;
                float a = accA[rt][j];
                float d = accC[rt][j] - a + bias;
                tA[rowL * 68 + colL] = f2bf(a);
                tD[rowL * 68 + colL] = f2bf(d);
            }
    }
    __syncthreads();

    // coalesced copy-out: thread -> (row r = tid>>2, 16-col seg = tid&3)
    {
        const int r  = tid >> 2;
        const int sg = tid & 3;
        const unsigned short* sa = tA + r * 68 + sg * 16;
        const unsigned short* sd = tD + r * 68 + sg * 16;
        unsigned short* da = Abf + (rb + r) * 256 + cb + sg * 16;
        unsigned short* dd = Dbf + (rb + r) * 256 + cb + sg * 16;
        *(short8*)(da)     = *(const short8*)(sa);
        *(short8*)(da + 8) = *(const short8*)(sa + 8);
        *(short8*)(dd)     = *(const short8*)(sd);
        *(short8*)(dd + 8) = *(const short8*)(sd + 8);
    }
}

// ---------------- K3: fused gather + gelu + GEMM2 + gelu + mean [R9-verbatim] -----
__global__ __launch_bounds__(256) void mlp_kernel(
        const unsigned short* __restrict__ Abf, const unsigned short* __restrict__ Dbf,
        const unsigned short* __restrict__ W2t, const float* __restrict__ b2,
        const int* __restrict__ idx, float* __restrict__ out) {
    __shared__ unsigned short sh[64 * 264];   // padded stride 264
    const int tid = threadIdx.x;
    const int qb  = blockIdx.x << 2;

    // Phase 0: build h1 = gelu(A[nb] + D[gq]) as bf16 in LDS
    {
        const int r   = ((tid >> 6) << 4) | (tid & 15);   // row 0..63 (= qlocal*16+k)
        const int seg = (tid >> 4) & 3;                   // 64-col segment
        const int gq  = qb + (r >> 4);
        const int nb  = idx[(gq << 4) + (r & 15)];
        const unsigned short* arow = Abf + nb * 256 + seg * 64;
        const unsigned short* drow = Dbf + gq * 256 + seg * 64;
        unsigned short* dst = sh + r * 264 + seg * 64;
#pragma unroll
        for (int u = 0; u < 8; ++u) {
            short8 av = *(const short8*)(arow + u * 8);
            short8 dv = *(const short8*)(drow + u * 8);
            short8 hv;
#pragma unroll
            for (int e = 0; e < 8; ++e) {
                float h = bf2f(av[e]) + bf2f(dv[e]);
                hv[e] = (short)f2bf(gelu_fast(h));
            }
            *(short8*)(dst + u * 8) = hv;
        }
    }
    __syncthreads();

    const int lane = tid & 63, wv = tid >> 6;
    const int m = lane & 15, quad = lane >> 4;
    const int ko0 = quad * 8;

    // Phase 2: h2 = gelu(h1 @ W2 + b2)  (64x128 = 4 row-tiles x 2 col-tiles/wave)
    f32x4 acc2[8];
#pragma unroll
    for (int i = 0; i < 8; ++i) acc2[i] = (f32x4){0.f, 0.f, 0.f, 0.f};
#pragma unroll
    for (int ks = 0; ks < 8; ++ks) {
        const int ko = ks * 32 + ko0;
        short8 af[4], bfr[2];
#pragma unroll
        for (int rt = 0; rt < 4; ++rt)
            af[rt] = *(const short8*)(sh + (rt * 16 + m) * 264 + ko);
#pragma unroll
        for (int ct = 0; ct < 2; ++ct)
            bfr[ct] = *(const short8*)(W2t + (wv * 32 + ct * 16 + m) * 256 + ko);
#pragma unroll
        for (int rt = 0; rt < 4; ++rt)
#pragma unroll
            for (int ct = 0; ct < 2; ++ct)
                acc2[rt * 2 + ct] = __builtin_amdgcn_mfma_f32_16x16x32_bf16(
                    af[rt], bfr[ct], acc2[rt * 2 + ct], 0, 0, 0);
    }

    // Epilogue: bias + gelu, mean over K=16, store f32
#pragma unroll
    for (int ct = 0; ct < 2; ++ct) {
        const int col = wv * 32 + ct * 16 + m;
        const float bias = b2[col];
#pragma unroll
        for (int rt = 0; rt < 4; ++rt) {
            float s = 0.f;
#pragma unroll
            for (int j = 0; j < 4; ++j)
                s += gelu_fast(acc2[rt * 2 + ct][j] + bias);
            s += __shfl_xor(s, 16, 64);
            s += __shfl_xor(s, 32, 64);
            if (quad == 0) out[(qb + rt) * 128 + col] = s * 0.0625f;
        }
    }
}

extern "C" void kernel_launch(void* const* d_in, const int* in_sizes, int n_in,
                              void* d_out, int out_size, void* d_ws, size_t ws_size,
                              hipStream_t stream) {
    const float* x      = (const float*)d_in[0];   // (1,8192,128)
    const float* points = (const float*)d_in[1];   // (1,8192,2)
    const float* W1     = (const float*)d_in[2];   // (256,256)
    const float* b1     = (const float*)d_in[3];   // (256,)
    const float* W2     = (const float*)d_in[4];   // (256,128)
    const float* b2     = (const float*)d_in[5];   // (128,)
    float* out = (float*)d_out;

    char* ws = (char*)d_ws;
    unsigned short* W1t = (unsigned short*)ws;                   // 131072 B
    unsigned short* W2t = (unsigned short*)(ws + 131072);        //  65536 B
    int*            idx = (int*)(ws + 196608);                   // 524288 B
    unsigned short* Abf = (unsigned short*)(ws + 720896);        // 4 MiB
    unsigned short* Dbf = (unsigned short*)(ws + 4915200);       // 4 MiB

    knn_kernel<<<2432, 256, 0, stream>>>(points, W1, W2, W1t, W2t, idx);
    gemmAD_kernel<<<512, 256, 0, stream>>>(x, W1t, b1, Abf, Dbf);
    mlp_kernel<<<2048, 256, 0, stream>>>(Abf, Dbf, W2t, b2, idx, out);
}

// Round 8
// 130.631 us; speedup vs baseline: 1.0078x; 1.0078x over previous
//
#include <hip/hip_runtime.h>

typedef __attribute__((ext_vector_type(8))) short short8;
typedef __attribute__((ext_vector_type(4))) float f32x4;

__device__ __forceinline__ unsigned short f2bf(float f) {
    unsigned int u = __float_as_uint(f);
    unsigned int r = u + 0x7fffu + ((u >> 16) & 1u);  // RNE
    return (unsigned short)(r >> 16);
}

__device__ __forceinline__ float bf2f(short s) {
    return __uint_as_float(((unsigned int)(unsigned short)s) << 16);
}

// tanh-form gelu: x * sigmoid(2*sqrt(2/pi)*(x + 0.044715 x^3))
__device__ __forceinline__ float gelu_fast(float v) {
    float x2 = v * v;
    float s  = v * fmaf(-0.102943195f, x2, -2.3022077f);   // -2z*log2(e)
    float e  = __builtin_amdgcn_exp2f(s);
    return v * __builtin_amdgcn_rcpf(1.0f + e);
}

__device__ __forceinline__ unsigned int d2key(float d2) {
    unsigned int u = __float_as_uint(d2);
    return u ^ (((unsigned int)(((int)u) >> 31)) | 0x80000000u);
}

#define U64MAX 0xFFFFFFFFFFFFFFFFull

// FROZEN (R5/R7/R9-passing byte-form), parameterized operand names only —
// the op sequence (__fmul_rn/__fadd_rn/fmaf) is byte-identical. Do not touch.
// Evaluated ONLY for candidates (~20-30/query); hot scans use the provably
// superset approximate prefilter (KNN_SLACK below).
#define D2_FROM_Q(px, py, XI, YI, SQI)                                           \
    ({ const float sqj_ = __fadd_rn(__fmul_rn((px), (px)), __fmul_rn((py), (py))); \
       const float t_   = fmaf((YI), (py), __fmul_rn((XI), (px)));                 \
       const float s_   = __fadd_rn((SQI), sqj_);                                  \
       fmaf(-2.0f, t_, s_); })

// float bitonic for the threshold phase only (dependent chain is short: f32,
// 1 shuffle/stage; kept because its replacement costs more instructions).
__device__ __forceinline__ float bitonic64f(float v, int lane) {
#pragma unroll
    for (int k = 2; k <= 64; k <<= 1) {
#pragma unroll
        for (int j = k >> 1; j > 0; j >>= 1) {
            float pv = __shfl_xor(v, j, 64);
            const bool up  = ((lane & k) == 0);
            const bool low = ((lane & j) == 0);
            const float mn = fminf(v, pv);
            const float mx = fmaxf(v, pv);
            v = (up == low) ? mn : mx;
        }
    }
    return v;
}

// Exact-path candidate insertion: recompute FROZEN d2 + key, push to LDS.
__device__ __forceinline__ void insert_cand(
        unsigned long long* crow, int* cnt,
        float px, float py, float XI, float YI, float SQI, int i) {
    const float d2 = D2_FROM_Q(px, py, XI, YI, SQI);
    const unsigned int key = d2key(d2);
    int pos = atomicAdd(cnt, 1);
    if (pos < 128)
        crow[pos] = ((unsigned long long)key << 32) | (unsigned int)i;
}

// Superset-prefilter slack (see R1 derivation: approx-metric deviation from
// (exact d2 - sqi) is ~2e-5; 100x margin -> provable superset incl. ties).
#define KNN_SLACK 2.0e-3f

// ---------------- K1: wconv (blocks 0..383) + knn (blocks 384..2431) ----------
// R8 = R6/R7 knn with ONE change: extraction is rank-select instead of bitonic
// sort. rank(c) = #{m<n : cand[m] < c} over the LDS candidate list (broadcast
// reads, wave-uniform loop, no cross-lane shuffles, no dependent DS chain).
// u64 candidates embed distinct indices -> strict total order identical to the
// bitonic's (incl. duplicate-point tie-break by index); ranks are a
// permutation, n>=17 guaranteed by the threshold -> ranks 1..16 all present.
// Scan/threshold/insert paths byte-identical to R6/R7.
__global__ __launch_bounds__(256) void knn_kernel(
        const float* __restrict__ points,
        const float* __restrict__ W1, const float* __restrict__ W2,
        unsigned short* __restrict__ W1t, unsigned short* __restrict__ W2t,
        int* __restrict__ idx_out) {
    __shared__ float pmin[4][4][64];          // [query][wave][lane]
    __shared__ float tshr[4];
    __shared__ unsigned long long cand[4][128];
    __shared__ int ccnt[4];

    const int bid = blockIdx.x;
    const int tid = threadIdx.x;

    if (bid < 384) {                       // ---- wconv ----
        int g = bid * 256 + tid;
        if (g < 65536) {                   // W1: (256,256) -> W1t[c][d]
            int d = g >> 8, c = g & 255;
            W1t[c * 256 + d] = f2bf(W1[g]);
        } else if (g < 98304) {            // W2: (256,128) -> W2t[c][d]
            int g2 = g - 65536;
            int d = g2 >> 7, c = g2 & 127;
            W2t[c * 256 + d] = f2bf(W2[g2]);
        }
        return;
    }

    // ---- knn: 4 waves, 4 queries, each wave scans points [wv*2048,(wv+1)*2048)
    const int wv    = tid >> 6;
    const int lane  = tid & 63;
    const int qbase = (bid - 384) << 2;

    float xi[4], yi[4], sqi_[4], n2x[4], n2y[4];
#pragma unroll
    for (int t = 0; t < 4; ++t) {
        xi[t] = points[(qbase + t) * 2 + 0];
        yi[t] = points[(qbase + t) * 2 + 1];
        sqi_[t] = __fadd_rn(__fmul_rn(xi[t], xi[t]), __fmul_rn(yi[t], yi[t]));
        n2x[t] = -2.0f * xi[t];
        n2y[t] = -2.0f * yi[t];
    }

    const float4* p4 = (const float4*)points;     // 2 points per float4
    const float4* pw = p4 + wv * 1024 + lane;     // this wave's slice

    if (tid < 4) ccnt[tid] = 0;

    // ---- scan 1: per-lane minimum of approx metric, per query ----
    float vmn[4] = {1e30f, 1e30f, 1e30f, 1e30f};
#pragma unroll 4
    for (int j = 0; j < 16; ++j) {
        const float4 pp = pw[j * 64];
        const float sqa = fmaf(pp.x, pp.x, pp.y * pp.y);
        const float sqb = fmaf(pp.z, pp.z, pp.w * pp.w);
#pragma unroll
        for (int t = 0; t < 4; ++t) {
            const float da = fmaf(n2x[t], pp.x, fmaf(n2y[t], pp.y, sqa));
            const float db = fmaf(n2x[t], pp.z, fmaf(n2y[t], pp.w, sqb));
            vmn[t] = fminf(fminf(da, db), vmn[t]);   // v_min3 candidate
        }
    }
#pragma unroll
    for (int t = 0; t < 4; ++t) pmin[t][wv][lane] = vmn[t];
    __syncthreads();

    // ---- 17th-smallest combined lane-min + slack = safe superset threshold --
    {
        const int q = wv;                      // one query per wave
        const float m = fminf(fminf(pmin[q][0][lane], pmin[q][1][lane]),
                              fminf(pmin[q][2][lane], pmin[q][3][lane]));
        const float s = bitonic64f(m, lane);
        if (lane == 16) tshr[q] = s + KNN_SLACK;
    }
    __syncthreads();
    float Ta[4];
#pragma unroll
    for (int t = 0; t < 4; ++t) Ta[t] = tshr[t];

    // ---- scan 2: approx prefilter, exact FROZEN recompute on hit ----
#pragma unroll 4
    for (int j = 0; j < 16; ++j) {
        const float4 pp = pw[j * 64];
        const int i0 = (wv * 1024 + j * 64 + lane) * 2;
        const float sqa = fmaf(pp.x, pp.x, pp.y * pp.y);
        const float sqb = fmaf(pp.z, pp.z, pp.w * pp.w);
#pragma unroll
        for (int t = 0; t < 4; ++t) {
            const float da = fmaf(n2x[t], pp.x, fmaf(n2y[t], pp.y, sqa));
            const float db = fmaf(n2x[t], pp.z, fmaf(n2y[t], pp.w, sqb));
            if (fminf(da, db) <= Ta[t]) {
                if (da <= Ta[t])
                    insert_cand(cand[t], &ccnt[t],
                                pp.x, pp.y, xi[t], yi[t], sqi_[t], i0);
                if (db <= Ta[t])
                    insert_cand(cand[t], &ccnt[t],
                                pp.z, pp.w, xi[t], yi[t], sqi_[t], i0 + 1);
            }
        }
    }
    __syncthreads();

    // ---- extraction: rank-select (R8) ----
    {
        const int q = qbase + wv;
        const unsigned long long* candw = cand[wv];
        const int cc = ccnt[wv];
        const int n = cc < 128 ? cc : 128;
        const unsigned long long c0 = (lane < n)      ? candw[lane]      : U64MAX;
        const unsigned long long c1 = (lane + 64 < n) ? candw[lane + 64] : U64MAX;
        int r0 = 0, r1 = 0;
        for (int mI = 0; mI < n; ++mI) {
            const unsigned long long cm = candw[mI];   // LDS broadcast
            r0 += (cm < c0) ? 1 : 0;
            r1 += (cm < c1) ? 1 : 0;
        }
        if (lane < n && r0 >= 1 && r0 <= 16)
            idx_out[q * 16 + r0 - 1] = (int)(unsigned int)(c0 & 0xFFFFFFFFull);
        if (lane + 64 < n && r1 >= 1 && r1 <= 16)
            idx_out[q * 16 + r1 - 1] = (int)(unsigned int)(c1 & 0xFFFFFFFFull);
    }
}

// ---------------- K2: A = x@W1[:128], D = x@W1[128:] - A + b1 (bf16) ----------
// R7 form (measured equal to R9 form; kept as current validated source).
__global__ __launch_bounds__(256) void gemmAD_kernel(
        const float* __restrict__ x, const unsigned short* __restrict__ W1t,
        const float* __restrict__ b1,
        unsigned short* __restrict__ Abf, unsigned short* __restrict__ Dbf) {
    __shared__ unsigned short sx[64 * 136];    // 64 rows x 128 bf16, stride 136
    __shared__ unsigned short tA[64 * 68];     // 64 x 64 out tile, stride 68
    __shared__ unsigned short tD[64 * 68];
    const int tid = threadIdx.x;
    const int rb  = (blockIdx.x >> 2) * 64;    // 128 row-tiles
    const int cb  = (blockIdx.x & 3) * 64;     // 4 col-tiles

    {   // stage x rows -> bf16 LDS (unchanged)
        const int r   = ((tid >> 6) << 4) | (tid & 15);   // row 0..63
        const int seg = (tid >> 4) & 3;                   // 32-float segment
        const float* xr = x + (rb + r) * 128 + seg * 32;
        unsigned short* dst = sx + r * 136 + seg * 32;
#pragma unroll
        for (int u = 0; u < 8; ++u) {
            float4 a = ((const float4*)xr)[u];
            uint2 w;
            w.x = (unsigned)f2bf(a.x) | ((unsigned)f2bf(a.y) << 16);
            w.y = (unsigned)f2bf(a.z) | ((unsigned)f2bf(a.w) << 16);
            *(uint2*)(dst + u * 4) = w;
        }
    }
    __syncthreads();

    const int lane = tid & 63, wv = tid >> 6;
    const int m = lane & 15, quad = lane >> 4;
    const int ko0 = quad * 8;

    f32x4 accA[4], accC[4];
#pragma unroll
    for (int i = 0; i < 4; ++i) { accA[i] = (f32x4){0,0,0,0}; accC[i] = (f32x4){0,0,0,0}; }

    const int colL = wv * 16 + m;              // local col 0..63

#pragma unroll
    for (int ks = 0; ks < 4; ++ks) {
        const int ko = ks * 32 + ko0;
        short8 af[4];
#pragma unroll
        for (int rt = 0; rt < 4; ++rt)
            af[rt] = *(const short8*)(sx + (rt * 16 + m) * 136 + ko);
        const unsigned short* wp = W1t + (cb + colL) * 256 + ko;
        const short8 bA = *(const short8*)(wp);         // d in [0,128)  -> A
        const short8 bC = *(const short8*)(wp + 128);   // d in [128,256)-> C
#pragma unroll
        for (int rt = 0; rt < 4; ++rt) {
            accA[rt] = __builtin_amdgcn_mfma_f32_16x16x32_bf16(af[rt], bA, accA[rt], 0, 0, 0);
            accC[rt] = __builtin_amdgcn_mfma_f32_16x16x32_bf16(af[rt], bC, accC[rt], 0, 0, 0);
        }
    }

    // epilogue: acc -> LDS tiles (bit-same values as R9 path)
    {
        const float bias = b1[cb + colL];
#pragma unroll
        for (int rt = 0; rt < 4; ++rt)
#pragma unroll
            for (int j = 0; j < 4; ++j) {
                const int rowL = rt * 16 + quad * 4 + j;
                float a = accA[rt][j];
                float d = accC[rt][j] - a + bias;
                tA[rowL * 68 + colL] = f2bf(a);
                tD[rowL * 68 + colL] = f2bf(d);
            }
    }
    __syncthreads();

    // coalesced copy-out: thread -> (row r = tid>>2, 16-col seg = tid&3)
    {
        const int r  = tid >> 2;
        const int sg = tid & 3;
        const unsigned short* sa = tA + r * 68 + sg * 16;
        const unsigned short* sd = tD + r * 68 + sg * 16;
        unsigned short* da = Abf + (rb + r) * 256 + cb + sg * 16;
        unsigned short* dd = Dbf + (rb + r) * 256 + cb + sg * 16;
        *(short8*)(da)     = *(const short8*)(sa);
        *(short8*)(da + 8) = *(const short8*)(sa + 8);
        *(short8*)(dd)     = *(const short8*)(sd);
        *(short8*)(dd + 8) = *(const short8*)(sd + 8);
    }
}

// ---------------- K3: fused gather + gelu + GEMM2 + gelu + mean [R9-verbatim] -----
__global__ __launch_bounds__(256) void mlp_kernel(
        const unsigned short* __restrict__ Abf, const unsigned short* __restrict__ Dbf,
        const unsigned short* __restrict__ W2t, const float* __restrict__ b2,
        const int* __restrict__ idx, float* __restrict__ out) {
    __shared__ unsigned short sh[64 * 264];   // padded stride 264
    const int tid = threadIdx.x;
    const int qb  = blockIdx.x << 2;

    // Phase 0: build h1 = gelu(A[nb] + D[gq]) as bf16 in LDS
    {
        const int r   = ((tid >> 6) << 4) | (tid & 15);   // row 0..63 (= qlocal*16+k)
        const int seg = (tid >> 4) & 3;                   // 64-col segment
        const int gq  = qb + (r >> 4);
        const int nb  = idx[(gq << 4) + (r & 15)];
        const unsigned short* arow = Abf + nb * 256 + seg * 64;
        const unsigned short* drow = Dbf + gq * 256 + seg * 64;
        unsigned short* dst = sh + r * 264 + seg * 64;
#pragma unroll
        for (int u = 0; u < 8; ++u) {
            short8 av = *(const short8*)(arow + u * 8);
            short8 dv = *(const short8*)(drow + u * 8);
            short8 hv;
#pragma unroll
            for (int e = 0; e < 8; ++e) {
                float h = bf2f(av[e]) + bf2f(dv[e]);
                hv[e] = (short)f2bf(gelu_fast(h));
            }
            *(short8*)(dst + u * 8) = hv;
        }
    }
    __syncthreads();

    const int lane = tid & 63, wv = tid >> 6;
    const int m = lane & 15, quad = lane >> 4;
    const int ko0 = quad * 8;

    // Phase 2: h2 = gelu(h1 @ W2 + b2)  (64x128 = 4 row-tiles x 2 col-tiles/wave)
    f32x4 acc2[8];
#pragma unroll
    for (int i = 0; i < 8; ++i) acc2[i] = (f32x4){0.f, 0.f, 0.f, 0.f};
#pragma unroll
    for (int ks = 0; ks < 8; ++ks) {
        const int ko = ks * 32 + ko0;
        short8 af[4], bfr[2];
#pragma unroll
        for (int rt = 0; rt < 4; ++rt)
            af[rt] = *(const short8*)(sh + (rt * 16 + m) * 264 + ko);
#pragma unroll
        for (int ct = 0; ct < 2; ++ct)
            bfr[ct] = *(const short8*)(W2t + (wv * 32 + ct * 16 + m) * 256 + ko);
#pragma unroll
        for (int rt = 0; rt < 4; ++rt)
#pragma unroll
            for (int ct = 0; ct < 2; ++ct)
                acc2[rt * 2 + ct] = __builtin_amdgcn_mfma_f32_16x16x32_bf16(
                    af[rt], bfr[ct], acc2[rt * 2 + ct], 0, 0, 0);
    }

    // Epilogue: bias + gelu, mean over K=16, store f32
#pragma unroll
    for (int ct = 0; ct < 2; ++ct) {
        const int col = wv * 32 + ct * 16 + m;
        const float bias = b2[col];
#pragma unroll
        for (int rt = 0; rt < 4; ++rt) {
            float s = 0.f;
#pragma unroll
            for (int j = 0; j < 4; ++j)
                s += gelu_fast(acc2[rt * 2 + ct][j] + bias);
            s += __shfl_xor(s, 16, 64);
            s += __shfl_xor(s, 32, 64);
            if (quad == 0) out[(qb + rt) * 128 + col] = s * 0.0625f;
        }
    }
}

extern "C" void kernel_launch(void* const* d_in, const int* in_sizes, int n_in,
                              void* d_out, int out_size, void* d_ws, size_t ws_size,
                              hipStream_t stream) {
    const float* x      = (const float*)d_in[0];   // (1,8192,128)
    const float* points = (const float*)d_in[1];   // (1,8192,2)
    const float* W1     = (const float*)d_in[2];   // (256,256)
    const float* b1     = (const float*)d_in[3];   // (256,)
    const float* W2     = (const float*)d_in[4];   // (256,128)
    const float* b2     = (const float*)d_in[5];   // (128,)
    float* out = (float*)d_out;

    char* ws = (char*)d_ws;
    unsigned short* W1t = (unsigned short*)ws;                   // 131072 B
    unsigned short* W2t = (unsigned short*)(ws + 131072);        //  65536 B
    int*            idx = (int*)(ws + 196608);                   // 524288 B
    unsigned short* Abf = (unsigned short*)(ws + 720896);        // 4 MiB
    unsigned short* Dbf = (unsigned short*)(ws + 4915200);       // 4 MiB

    knn_kernel<<<2432, 256, 0, stream>>>(points, W1, W2, W1t, W2t, idx);
    gemmAD_kernel<<<512, 256, 0, stream>>>(x, W1t, b1, Abf, Dbf);
    mlp_kernel<<<2048, 256, 0, stream>>>(Abf, Dbf, W2t, b2, idx, out);
}